// Round 4
// baseline (1253.826 us; speedup 1.0000x reference)
//
#include <hip/hip_runtime.h>
#include <hip/hip_bf16.h>
#include <hip/hip_cooperative_groups.h>

namespace cg = cooperative_groups;

#define DEV __device__ __forceinline__

typedef unsigned short u16;
typedef short bf16x8_t __attribute__((ext_vector_type(8)));
typedef float f32x4_t __attribute__((ext_vector_type(4)));

// Model dims: B=256 H=1024 F=512 P=66 T_IN=10 T_OUT=25, gates 4H=4096
// enc K = F+H = 1536 ; dec split: grp1 hd@Wx (K=1024) + grp2 atth@whh (K=1024)
constexpr int NBLK = 256;
constexpr int NTHR = 512;
constexpr int NT_ALL = NBLK * NTHR;
constexpr size_t HSTRIDE = 256 * 1024;
constexpr int SMEM_BYTES = 98304;   // dynamic LDS: A 4x8KB @0, B 4x16KB @32K

struct Params {
  const float *x, *z, *resid, *tf_w, *tf_b;
  const float *e_wih, *e_whh, *e_bih, *e_bhh;
  const float *p_wih, *p_whh, *p_bih, *p_bhh;
  const float *d_wih, *d_whh, *d_bih, *d_bhh;
  const float *lin_w, *lin_b, *tp_w, *tp_b;
  u16 *Wenc, *Wencp, *Wdec, *wihP, *linT, *tpw;
  float *bias_e, *bias_ep, *bias_d, *bias_part;
  u16 *xf, *zf;
  u16 *he, *hp;            // 11 step-buffers each
  u16 *hs;                 // 25 decoder h buffers
  u16 *atth;               // 25 step-buffers
  float *c_pub;            // 2 ping-pong f32 [256][1024]
  unsigned long long *p1;  // 128 tiles x 4096 u64 (gemm1 f32 partials)
  unsigned *flag1;         // 128 flags, 64B stride
  unsigned *bar;           // ctr[i*16]: 0..7 full, 8..11 grp1, 12..15 grp2
  float *out;
};

DEV float b2f(u16 v) { unsigned u = ((unsigned)v) << 16; float f; __builtin_memcpy(&f, &u, 4); return f; }
DEV u16 f2b(float f) {
  unsigned u; __builtin_memcpy(&u, &f, 4);
  unsigned r = u + 0x7fffu + ((u >> 16) & 1u);   // RNE
  return (u16)(r >> 16);
}
DEV unsigned pk2(float a, float b) { return (unsigned)f2b(a) | ((unsigned)f2b(b) << 16); }
DEV uint4 cvt8(const float* s) {
  float4 a = *(const float4*)s;
  float4 b = *(const float4*)(s + 4);
  uint4 r;
  r.x = pk2(a.x, a.y); r.y = pk2(a.z, a.w);
  r.z = pk2(b.x, b.y); r.w = pk2(b.z, b.w);
  return r;
}
DEV float sigm(float x) { return 1.0f / (1.0f + __expf(-x)); }
DEV f32x4_t fzero4() { f32x4_t v = {0.f, 0.f, 0.f, 0.f}; return v; }

DEV void gll16(const void* g, void* l) {
  __builtin_amdgcn_global_load_lds(
      (const __attribute__((address_space(1))) void*)g,
      (__attribute__((address_space(3))) void*)l, 16, 0, 0);
}

template <typename T> DEV void st_wt(T* p, T v) {
  __hip_atomic_store(p, v, __ATOMIC_RELAXED, __HIP_MEMORY_SCOPE_AGENT);
}
template <typename T> DEV T ld_byp(const T* p) {
  return __hip_atomic_load(p, __ATOMIC_RELAXED, __HIP_MEMORY_SCOPE_AGENT);
}

// ---- fence-free barriers: monotonic counters, no cache flush ----
DEV void fullbar(unsigned* ctrs, int myidx, unsigned tgt, int tid) {
  asm volatile("s_waitcnt vmcnt(0)" ::: "memory");
  __syncthreads();
  if (tid == 0) atomicAdd(&ctrs[myidx * 16], 1u);
  if (tid < 8) { while (ld_byp(&ctrs[tid * 16]) < tgt) __builtin_amdgcn_s_sleep(2); }
  __syncthreads();
}
DEV void gbar(unsigned* ctrs, int cbase, int myidx, unsigned tgt, int tid) {
  asm volatile("s_waitcnt vmcnt(0)" ::: "memory");
  __syncthreads();
  if (tid == 0) atomicAdd(&ctrs[(cbase + myidx) * 16], 1u);
  if (tid < 4) { while (ld_byp(&ctrs[(cbase + tid) * 16]) < tgt) __builtin_amdgcn_s_sleep(2); }
  __syncthreads();
}
DEV void spectate(unsigned* ctrs, int cbase, unsigned tgt, int tid) {
  if (tid < 4) { while (ld_byp(&ctrs[(cbase + tid) * 16]) < tgt) __builtin_amdgcn_s_sleep(2); }
  __syncthreads();
}

// ------------- 64m x 128n tile bf16 GEMM, 8 waves of 32x32 ----------------
// LDS: lA = sm[0..32K) 4 slots x 8KB; lB = sm[32K..96K) 4 slots x 16KB.
// slot(ks) = (ks+2)&3  (prestage of ks=0,1 lands in high slots 2,3 which are
// never aliased by the attention/epilogue overlays at sm[0..51K)).
// Source-side XOR swizzle (16B unit ^= row&7) + same XOR on ds_read_b128.
// PM: 0 = stage A+B slots 0,1 at entry; 1 = caller prestaged A+B slots 0,1;
//     2 = caller prestaged B slots 0,1; A staged at entry.
template <int PM>
DEV void gemm64(const u16* __restrict__ xa, int ldx, int xcols,
                const u16* __restrict__ ha, int ldh,
                const u16* __restrict__ wsrc, int ldw, int K,
                int m0, int n0, int tid, char* sm, f32x4_t acc[4]) {
  char* lA = sm;
  char* lB = sm + 32768;
  const int NK = K >> 6;
  const int row = tid >> 3;
  const int usw = ((tid & 7) ^ (row & 7)) * 8;
  const int wv = tid >> 6;
  char* laD = lA + (wv << 10);
  char* lbD = lB + (wv << 10);
  const u16* aX = xa + (size_t)(m0 + row) * ldx + usw;
  const u16* aH = ha + (size_t)(m0 + row) * ldh + usw - xcols;
  const u16* bW0 = wsrc + (size_t)(n0 + row) * ldw + usw;
  const u16* bW1 = bW0 + (size_t)64 * ldw;

  auto sA = [&](int ks) {
    const int k0 = ks << 6;
    const u16* g = (k0 < xcols) ? (aX + k0) : (aH + k0);
    gll16(g, laD + (((ks + 2) & 3) << 13));
  };
  auto sB = [&](int ks) {
    const int k0 = ks << 6;
    const int so = ((ks + 2) & 3) << 14;
    gll16(bW0 + k0, lbD + so);
    gll16(bW1 + k0, lbD + so + 8192);
  };

  const int l = tid & 63, l15 = l & 15, lhi = l >> 4;
  const int wr = wv >> 2, wc = wv & 3;   // 2m x 4n wave grid, 32x32 wave tile
  const int rA0 = wr * 32 + l15, rA1 = rA0 + 16;
  const int nB0 = wc * 32 + l15, nB1 = nB0 + 16;
  const int a00 = rA0 * 128 + ((lhi ^ (rA0 & 7)) << 4);
  const int a01 = rA0 * 128 + (((lhi + 4) ^ (rA0 & 7)) << 4);
  const int a10 = rA1 * 128 + ((lhi ^ (rA1 & 7)) << 4);
  const int a11 = rA1 * 128 + (((lhi + 4) ^ (rA1 & 7)) << 4);
  const int b00 = nB0 * 128 + ((lhi ^ (nB0 & 7)) << 4);
  const int b01 = nB0 * 128 + (((lhi + 4) ^ (nB0 & 7)) << 4);
  const int b10 = nB1 * 128 + ((lhi ^ (nB1 & 7)) << 4);
  const int b11 = nB1 * 128 + (((lhi + 4) ^ (nB1 & 7)) << 4);

  if (PM == 0) { sA(0); sB(0); sA(1); sB(1); }
  if (PM == 2) { sA(0); sA(1); }

#pragma unroll 1
  for (int ks = 0; ks < NK; ++ks) {
    if (ks + 2 < NK) { sA(ks + 2); sB(ks + 2); }
    if (PM == 2 && ks == 0)  asm volatile("s_waitcnt vmcnt(4)" ::: "memory");
    else if (ks + 2 < NK)    asm volatile("s_waitcnt vmcnt(6)" ::: "memory");
    else if (ks + 2 == NK)   asm volatile("s_waitcnt vmcnt(3)" ::: "memory");
    else                     asm volatile("s_waitcnt vmcnt(0)" ::: "memory");
    __builtin_amdgcn_s_barrier();
    const char* A  = lA + (((ks + 2) & 3) << 13);
    const char* Bq = lB + (((ks + 2) & 3) << 14);
#pragma unroll
    for (int kh = 0; kh < 2; ++kh) {
      bf16x8_t va0 = *(const bf16x8_t*)(A + (kh ? a01 : a00));
      bf16x8_t va1 = *(const bf16x8_t*)(A + (kh ? a11 : a10));
      bf16x8_t vb0 = *(const bf16x8_t*)(Bq + (kh ? b01 : b00));
      bf16x8_t vb1 = *(const bf16x8_t*)(Bq + (kh ? b11 : b10));
      acc[0] = __builtin_amdgcn_mfma_f32_16x16x32_bf16(va0, vb0, acc[0], 0, 0, 0);
      acc[1] = __builtin_amdgcn_mfma_f32_16x16x32_bf16(va0, vb1, acc[1], 0, 0, 0);
      acc[2] = __builtin_amdgcn_mfma_f32_16x16x32_bf16(va1, vb0, acc[2], 0, 0, 0);
      acc[3] = __builtin_amdgcn_mfma_f32_16x16x32_bf16(va1, vb1, acc[3], 0, 0, 0);
    }
  }
  asm volatile("s_waitcnt lgkmcnt(0)" ::: "memory");
  __builtin_amdgcn_s_barrier();
}

// Prestage helpers (must match gemm64's addressing/slot mapping exactly)
DEV void preA(const u16* src, int lds_, int m0, int tid, char* sm, int ks) {
  const int row = tid >> 3, usw = ((tid & 7) ^ (row & 7)) * 8, wv = tid >> 6;
  gll16(src + (size_t)(m0 + row) * lds_ + (ks << 6) + usw,
        sm + (wv << 10) + (((ks + 2) & 3) << 13));
}
DEV void preB(const u16* w, int ldw, int n0, int tid, char* sm, int ks) {
  const int row = tid >> 3, usw = ((tid & 7) ^ (row & 7)) * 8, wv = tid >> 6;
  char* d = sm + 32768 + (wv << 10) + (((ks + 2) & 3) << 14);
  gll16(w + (size_t)(n0 + row) * ldw + (ks << 6) + usw, d);
  gll16(w + (size_t)(n0 + 64 + row) * ldw + (ks << 6) + usw, d + 8192);
}

// ----------------- LSTM pointwise epilogue, c in registers -----------------
// Overlay [64][128] f32 at sm[0..32K) (aliases A slots; B slots 2,3 survive).
DEV void lstm_ep(const f32x4_t acc[4], int tid, char* sm,
                 const float* __restrict__ bias, float cc[4],
                 const float* __restrict__ cinit,
                 u16* __restrict__ hw, float* __restrict__ cpub,
                 int m0, int n0) {
  float* gl = (float*)sm;
  const int l = tid & 63, l15 = l & 15, lhi = l >> 4;
  const int wv = tid >> 6, wr = wv >> 2, wc = wv & 3;
#pragma unroll
  for (int mf = 0; mf < 2; ++mf)
#pragma unroll
    for (int nf = 0; nf < 2; ++nf)
#pragma unroll
      for (int qq = 0; qq < 4; ++qq)
        gl[(wr * 32 + mf * 16 + lhi * 4 + qq) * 128 + wc * 32 + nf * 16 + l15] =
            acc[mf * 2 + nf][qq];
  __syncthreads();
#pragma unroll
  for (int it = 0; it < 4; ++it) {
    int idx = it * 512 + tid;            // 2048 items: 64 rows x 32 j
    int r = idx >> 5, jj = idx & 31;
    f32x4_t g4 = *(const f32x4_t*)(gl + r * 128 + jj * 4);
    f32x4_t b4 = *(const f32x4_t*)(bias + n0 + jj * 4);
    float ig = sigm(g4[0] + b4[0]);
    float fg = sigm(g4[1] + b4[1]);
    float g_ = tanhf(g4[2] + b4[2]);
    float og = sigm(g4[3] + b4[3]);
    size_t off = (size_t)(m0 + r) * 1024 + (n0 >> 2) + jj;
    float cold = cinit ? ld_byp(cinit + off) : cc[it];
    float cn = fg * cold + ig * g_;
    cc[it] = cn;
    float hn = og * tanhf(cn);
    st_wt(&hw[off], f2b(hn));
    if (cpub) st_wt(&cpub[off], cn);
  }
  __syncthreads();
}

DEV void wx_store(const f32x4_t acc[4], int tid, u16* __restrict__ Wdec,
                  int m0, int n0) {
  const int l = tid & 63, l15 = l & 15, lhi = l >> 4;
  const int wv = tid >> 6, wr = wv >> 2, wc = wv & 3;
#pragma unroll
  for (int mf = 0; mf < 2; ++mf)
#pragma unroll
    for (int nf = 0; nf < 2; ++nf)
#pragma unroll
      for (int qq = 0; qq < 4; ++qq) {
        int r = m0 + wr * 32 + mf * 16 + lhi * 4 + qq;
        int c = n0 + wc * 32 + nf * 16 + l15;
        st_wt(&Wdec[(size_t)r * 2048 + c], f2b(acc[mf * 2 + nf][qq]));
      }
}

// gemm1 partial exchange (lane-frag layout: zero remap cost)
DEV void p1_store(const f32x4_t acc[4], int tid, unsigned long long* base) {
  unsigned long long* d = base + (size_t)tid * 8;
#pragma unroll
  for (int i = 0; i < 8; ++i) {
    float lo = acc[i >> 1][(i & 1) * 2 + 0];
    float hi = acc[i >> 1][(i & 1) * 2 + 1];
    unsigned a_, b_; __builtin_memcpy(&a_, &lo, 4); __builtin_memcpy(&b_, &hi, 4);
    st_wt(d + i, (unsigned long long)a_ | ((unsigned long long)b_ << 32));
  }
}
DEV void p1_merge(f32x4_t acc[4], int tid, const unsigned long long* base) {
  const unsigned long long* s_ = base + (size_t)tid * 8;
#pragma unroll
  for (int i = 0; i < 8; ++i) {
    unsigned long long u = ld_byp(s_ + i);
    unsigned a_ = (unsigned)u, b_ = (unsigned)(u >> 32);
    float lo, hi; __builtin_memcpy(&lo, &a_, 4); __builtin_memcpy(&hi, &b_, 4);
    acc[i >> 1][(i & 1) * 2 + 0] += lo;
    acc[i >> 1][(i & 1) * 2 + 1] += hi;
  }
}

// ------------------- phase 0: ToFeature (block-cooperative) ----------------
DEV void phase0_tf(const Params& p, int bid, int tid, char* sm) {
  float* xs = (float*)sm;            // [10][66]
  float* zs = (float*)(sm + 2688);
  for (int g = tid; g < 660; g += NTHR) {
    int t = g / 66, qd = g - t * 66;
    xs[g] = p.x[((size_t)bid * 10 + t) * 66 + qd];
    zs[g] = p.z[((size_t)bid * 10 + t) * 66 + qd];
  }
  __syncthreads();
  const int n = tid;
  float accx[10], accz[10];
  float bn = p.tf_b[n];
#pragma unroll
  for (int t = 0; t < 10; ++t) { accx[t] = bn; accz[t] = bn; }
  const float* wrow = p.tf_w + (size_t)n * 66;
  for (int k = 0; k < 66; ++k) {
    float wk = wrow[k];
#pragma unroll
    for (int t = 0; t < 10; ++t) {
      accx[t] = fmaf(wk, xs[t * 66 + k], accx[t]);
      accz[t] = fmaf(wk, zs[t * 66 + k], accz[t]);
    }
  }
#pragma unroll
  for (int t = 0; t < 10; ++t) {
    p.xf[(size_t)t * 131072 + (size_t)bid * 512 + n] = f2b(accx[t]);
    p.zf[(size_t)t * 131072 + (size_t)bid * 512 + n] = f2b(accz[t]);
  }
  __syncthreads();
}

// --------------------------- phase 0a: conversions -------------------------
DEV void phase0a(const Params& p, int gtid) {
  for (int g = gtid; g < 786432; g += NT_ALL) {     // enc/encp 4096 x 192 units
    int row = g / 192;
    int u = g - row * 192;
    int k = u * 8;
    int nsrc = (row & 3) * 1024 + (row >> 2);       // gate-interleaved rows
    const float* s1 = (k < 512) ? (p.e_wih + (size_t)nsrc * 512 + k)
                                : (p.e_whh + (size_t)nsrc * 1024 + (k - 512));
    ((uint4*)p.Wenc)[g] = cvt8(s1);
    const float* s2 = (k < 512) ? (p.p_wih + (size_t)nsrc * 512 + k)
                                : (p.p_whh + (size_t)nsrc * 1024 + (k - 512));
    ((uint4*)p.Wencp)[g] = cvt8(s2);
  }
  for (int g = gtid; g < 524288; g += NT_ALL) {     // dec whh -> Wdec[:,1024:]
    int row = g >> 7, u = g & 127;
    int nsrc = (row & 3) * 1024 + (row >> 2);
    ((uint4*)p.Wdec)[row * 256 + 128 + u] = cvt8(p.d_whh + (size_t)nsrc * 1024 + u * 8);
  }
  for (int g = gtid; g < 262144; g += NT_ALL) {     // dec wih (gate-permuted)
    int row = g >> 6, u = g & 63;
    int nsrc = (row & 3) * 1024 + (row >> 2);
    ((uint4*)p.wihP)[g] = cvt8(p.d_wih + (size_t)nsrc * 512 + u * 8);
  }
  for (int g = gtid; g < 524288; g += NT_ALL) {     // lin_w transpose
    int f = g >> 10, h = g & 1023;
    p.linT[(size_t)h * 512 + f] = f2b(p.lin_w[g]);
  }
  for (int g = gtid; g < 8448; g += NT_ALL)
    ((uint4*)p.tpw)[g] = cvt8(p.tp_w + g * 8);
  for (int g = gtid; g < 4096; g += NT_ALL) {       // enc biases
    int nsrc = (g & 3) * 1024 + (g >> 2);
    p.bias_e[g]  = p.e_bih[nsrc] + p.e_bhh[nsrc];
    p.bias_ep[g] = p.p_bih[nsrc] + p.p_bhh[nsrc];
  }
  for (int g = gtid; g < 32768; g += NT_ALL) {      // bias_d partials (wih@lin_b)
    int cell = g >> 3, sub = g & 7;
    int nsrc = (cell & 3) * 1024 + (cell >> 2);
    const float* wr_ = p.d_wih + (size_t)nsrc * 512 + sub * 64;
    const float* lb = p.lin_b + sub * 64;
    float s = 0.f;
    for (int f = 0; f < 64; ++f) s += wr_[f] * lb[f];
    p.bias_part[g] = s;
  }
  uint4 zz; zz.x = zz.y = zz.z = zz.w = 0u;         // zero h0 for both encoders
  for (int g = gtid; g < 32768; g += NT_ALL) { ((uint4*)p.he)[g] = zz; ((uint4*)p.hp)[g] = zz; }
}

// --------------------------- attention (1 row / call) ----------------------
// LDS: catl at sm[0..43008), cl at +43008, sc at +47104 (< 49152; B slots 2,3
// at sm[64K..96K) survive).
DEV void attention(const Params& p, const u16* hd_prev, const float* cpub,
                   u16* atth_s, int b, int tid, char* sm) {
  u16*   catl = (u16*)sm;
  float* cl   = (float*)(sm + 43008);
  float* sc   = (float*)(sm + 47104);
  for (int g = tid; g < 2688; g += NTHR) {
    int t = g >> 7, hu = g & 127;
    const u16* src;
    if (t < 10)       src = p.he + (size_t)(t + 1) * HSTRIDE;
    else if (t == 10) src = hd_prev;
    else              src = p.hp + (size_t)(t - 10) * HSTRIDE;
    ((uint4*)catl)[g] = *(const uint4*)(src + (size_t)b * 1024 + hu * 8);
  }
  for (int g = tid; g < 512; g += NTHR) {
    unsigned long long v = ld_byp(((const unsigned long long*)(cpub + (size_t)b * 1024)) + g);
    ((unsigned long long*)cl)[g] = v;
  }
  __syncthreads();
  const int wv = tid >> 6, l = tid & 63;
  for (int t = wv; t < 21; t += 8) {
    float s = 0.f;
    const u16* cr = catl + t * 1024;
    for (int hh = l; hh < 1024; hh += 64) s += cl[hh] * b2f(cr[hh]);
#pragma unroll
    for (int o = 32; o; o >>= 1) s += __shfl_down(s, o);
    if (l == 0) sc[t] = s;
  }
  __syncthreads();
  float m = -1e30f;
#pragma unroll
  for (int t = 0; t < 21; ++t) m = fmaxf(m, sc[t]);
  float e[21]; float den = 0.f;
#pragma unroll
  for (int t = 0; t < 21; ++t) { e[t] = __expf(sc[t] - m); den += e[t]; }
  float inv = 1.0f / den;
  const int h0 = tid * 2;
  float a0 = 0.f, a1 = 0.f;
#pragma unroll
  for (int t = 0; t < 21; ++t) {
    float w_ = e[t] * inv;
    unsigned v = *(const unsigned*)(catl + t * 1024 + h0);
    a0 += w_ * b2f((u16)(v & 0xffff));
    a1 += w_ * b2f((u16)(v >> 16));
  }
  st_wt(((unsigned*)(atth_s + (size_t)b * 1024)) + tid, pk2(a0, a1));
  __syncthreads();
}

// ------------------------- final projection (1 b / block) ------------------
DEV void finalproj(const Params& p, int b, int tid, char* sm) {
  u16* hl = (u16*)sm;                     // [25][1024] bf16 = 51200 B
  for (int g = tid; g < 3200; g += NTHR) {
    int t = g >> 7, hu = g & 127;
    ((uint4*)hl)[g] = *(const uint4*)(p.hs + ((size_t)(t * 256 + b)) * 1024 + hu * 8);
  }
  __syncthreads();
  if (tid < 330) {
    int pcol = tid % 66, tg = tid / 66;
    float acc[5] = {0.f, 0.f, 0.f, 0.f, 0.f};
    const u16* wrow = p.tpw + (size_t)pcol * 1024;
    for (int hc = 0; hc < 128; ++hc) {
      uint4 wv4 = ((const uint4*)wrow)[hc];
      float wf[8];
      wf[0] = b2f(wv4.x & 0xffff); wf[1] = b2f(wv4.x >> 16);
      wf[2] = b2f(wv4.y & 0xffff); wf[3] = b2f(wv4.y >> 16);
      wf[4] = b2f(wv4.z & 0xffff); wf[5] = b2f(wv4.z >> 16);
      wf[6] = b2f(wv4.w & 0xffff); wf[7] = b2f(wv4.w >> 16);
#pragma unroll
      for (int r = 0; r < 5; ++r) {
        int t = tg * 5 + r;
        uint4 hv = ((const uint4*)(hl + t * 1024))[hc];
        float s;
        s  = wf[0] * b2f(hv.x & 0xffff) + wf[1] * b2f(hv.x >> 16);
        s += wf[2] * b2f(hv.y & 0xffff) + wf[3] * b2f(hv.y >> 16);
        s += wf[4] * b2f(hv.z & 0xffff) + wf[5] * b2f(hv.z >> 16);
        s += wf[6] * b2f(hv.w & 0xffff) + wf[7] * b2f(hv.w >> 16);
        acc[r] += s;
      }
    }
    float bb = p.tp_b[pcol];
#pragma unroll
    for (int r = 0; r < 5; ++r) {
      int t = tg * 5 + r;
      size_t o = (size_t)b * 1650 + (size_t)t * 66 + pcol;
      p.out[o] = acc[r] + bb + p.resid[o];
    }
  }
}

// ------------------------------- main kernel -------------------------------
__global__ __launch_bounds__(NTHR) void model_kernel(Params p) {
  cg::grid_group gg = cg::this_grid();
  extern __shared__ __align__(16) char sm[];
  const int tid = threadIdx.x;
  const int bid = blockIdx.x;
  const int gtid = bid * NTHR + tid;

  phase0_tf(p, bid, tid, sm);
  phase0a(p, gtid);
  if (bid == 0) {
    if (tid < 16)  st_wt(&p.bar[tid * 16], 0u);
    if (tid < 128) st_wt(&p.flag1[tid * 16], 0u);
  }
  gg.sync();                      // ONLY full-fence sync (flushes phase0 writes)

  // finalize bias_d
  for (int g = gtid; g < 4096; g += NT_ALL) {
    int nsrc = (g & 3) * 1024 + (g >> 2);
    float s = p.d_bih[nsrc] + p.d_bhh[nsrc];
#pragma unroll
    for (int k8 = 0; k8 < 8; ++k8) s += p.bias_part[g * 8 + k8];
    st_wt(&p.bias_d[g], s);
  }
  // P0b: Wdec[:,0:1024] = (gate-permuted dec_wih) @ lin_w  (lin fused)
#pragma unroll 1
  for (int i = 0; i < 2; ++i) {
    int tt = bid * 2 + i;
    int m0w = (tt & 63) << 6;
    int n0w = (tt >> 6) << 7;
    f32x4_t acc[4] = {fzero4(), fzero4(), fzero4(), fzero4()};
    gemm64<0>(p.wihP, 512, 512, p.wihP, 512, p.linT, 512, 512, m0w, n0w, tid, sm, acc);
    wx_store(acc, tid, p.Wdec, m0w, n0w);
  }

  // Group geometry: grp0 = enc + dec-gemm1; grp1 = encp + att + dec-gemm2/ep
  const int grp = bid >> 7;
  const int q = bid & 127;
  const int m0 = (q >> 5) << 6;
  const int n0 = (q & 31) << 7;
  const int cb = grp ? 12 : 8;
  const int cidx = q >> 5;

  const u16* xsrc = grp ? p.zf : p.xf;
  const u16* Wg   = grp ? p.Wencp : p.Wenc;
  u16* hbuf       = grp ? p.hp : p.he;
  const float* bias_g = grp ? p.bias_ep : p.bias_e;

  // prestage encoder t=0, then the post-setup full barrier
  preA(xsrc, 512, m0, tid, sm, 0);
  preB(Wg, 1536, n0, tid, sm, 0);
  preA(xsrc, 512, m0, tid, sm, 1);
  preB(Wg, 1536, n0, tid, sm, 1);
  fullbar(p.bar, bid & 7, 1u * 32, tid);

  float cc[4] = {0.f, 0.f, 0.f, 0.f};

  // P1: encoders, groups fully independent (128-block barriers)
#pragma unroll 1
  for (int t = 0; t < 10; ++t) {
    f32x4_t acc[4] = {fzero4(), fzero4(), fzero4(), fzero4()};
    gemm64<1>(xsrc + (size_t)t * 131072, 512, 512, hbuf + (size_t)t * HSTRIDE, 1024,
              Wg, 1536, 1536, m0, n0, tid, sm, acc);
    lstm_ep(acc, tid, sm, bias_g, cc, (const float*)0,
            hbuf + (size_t)(t + 1) * HSTRIDE,
            (!grp && t == 9) ? p.c_pub : (float*)0, m0, n0);
    if (t < 9) {
      preA(xsrc + (size_t)(t + 1) * 131072, 512, m0, tid, sm, 0);
      preB(Wg, 1536, n0, tid, sm, 0);
      preA(xsrc + (size_t)(t + 1) * 131072, 512, m0, tid, sm, 1);
      preB(Wg, 1536, n0, tid, sm, 1);
    } else {
      const u16* wd = grp ? (p.Wdec + 1024) : p.Wdec;
      preB(wd, 2048, n0, tid, sm, 0);
      preB(wd, 2048, n0, tid, sm, 1);
    }
    gbar(p.bar, cb, cidx, (unsigned)(t + 1) * 32, tid);
  }
  fullbar(p.bar, bid & 7, 2u * 32, tid);

  // P3: decoder. grp0 produces hd@Wx partials (paced by spectating grp1's
  // epoch counters); grp1 does att -> atth@whh -> merge -> epilogue.
  if (grp == 0) {
#pragma unroll 1
    for (int s = 0; s < 25; ++s) {
      if (s > 0) spectate(p.bar, 12, (unsigned)(10 + 2 * s) * 32, tid);
      const u16* hd_prev = (s == 0) ? (p.he + (size_t)10 * HSTRIDE)
                                    : (p.hs + (size_t)(s - 1) * HSTRIDE);
      f32x4_t acc[4] = {fzero4(), fzero4(), fzero4(), fzero4()};
      gemm64<2>(hd_prev, 1024, 1024, hd_prev, 1024, p.Wdec, 2048, 1024,
                m0, n0, tid, sm, acc);
      p1_store(acc, tid, p.p1 + (size_t)q * 4096);
      asm volatile("s_waitcnt vmcnt(0)" ::: "memory");
      __syncthreads();
      if (tid == 0) st_wt(&p.flag1[q * 16], (unsigned)(s + 1));
      preB(p.Wdec, 2048, n0, tid, sm, 0);
      preB(p.Wdec, 2048, n0, tid, sm, 1);
    }
    spectate(p.bar, 12, 60u * 32, tid);   // hs[24] ready
  } else {
    float cd[4] = {0.f, 0.f, 0.f, 0.f};
#pragma unroll 1
    for (int s = 0; s < 25; ++s) {
      const u16* hd_prev = (s == 0) ? (p.he + (size_t)10 * HSTRIDE)
                                    : (p.hs + (size_t)(s - 1) * HSTRIDE);
      u16* atth_s = p.atth + (size_t)s * HSTRIDE;
      const float* cp = p.c_pub + (size_t)(s & 1) * 262144;
      attention(p, hd_prev, cp, atth_s, 2 * q, tid, sm);
      attention(p, hd_prev, cp, atth_s, 2 * q + 1, tid, sm);
      gbar(p.bar, 12, cidx, (unsigned)(11 + 2 * s) * 32, tid);
      f32x4_t acc[4] = {fzero4(), fzero4(), fzero4(), fzero4()};
      gemm64<2>(atth_s, 1024, 1024, atth_s, 1024, p.Wdec + 1024, 2048, 1024,
                m0, n0, tid, sm, acc);
      if (tid == 0) {
        while (ld_byp(&p.flag1[q * 16]) < (unsigned)(s + 1)) __builtin_amdgcn_s_sleep(2);
      }
      __syncthreads();
      p1_merge(acc, tid, p.p1 + (size_t)q * 4096);
      lstm_ep(acc, tid, sm, p.bias_d, cd,
              (s == 0) ? p.c_pub : (const float*)0,
              p.hs + (size_t)s * HSTRIDE,
              p.c_pub + (size_t)((s + 1) & 1) * 262144, m0, n0);
      preB(p.Wdec + 1024, 2048, n0, tid, sm, 0);
      preB(p.Wdec + 1024, 2048, n0, tid, sm, 1);
      gbar(p.bar, 12, cidx, (unsigned)(12 + 2 * s) * 32, tid);
    }
  }

  // P4: out = dec_h @ tp_w.T + tp_b + for_resid
  finalproj(p, bid, tid, sm);
}

// ------------------------------- host launch -------------------------------
extern "C" void kernel_launch(void* const* d_in, const int* in_sizes, int n_in,
                              void* d_out, int out_size, void* d_ws, size_t ws_size,
                              hipStream_t stream) {
  (void)in_sizes; (void)n_in; (void)out_size;
  Params P;
  P.x     = (const float*)d_in[0];
  P.z     = (const float*)d_in[1];
  P.resid = (const float*)d_in[2];
  P.tf_w  = (const float*)d_in[3];
  P.tf_b  = (const float*)d_in[4];
  P.e_wih = (const float*)d_in[5];
  P.e_whh = (const float*)d_in[6];
  P.e_bih = (const float*)d_in[7];
  P.e_bhh = (const float*)d_in[8];
  P.p_wih = (const float*)d_in[9];
  P.p_whh = (const float*)d_in[10];
  P.p_bih = (const float*)d_in[11];
  P.p_bhh = (const float*)d_in[12];
  P.d_wih = (const float*)d_in[13];
  P.d_whh = (const float*)d_in[14];
  P.d_bih = (const float*)d_in[15];
  P.d_bhh = (const float*)d_in[16];
  P.lin_w = (const float*)d_in[17];
  P.lin_b = (const float*)d_in[18];
  P.tp_w  = (const float*)d_in[19];
  P.tp_b  = (const float*)d_in[20];

  char* w = (char*)d_ws;
  size_t o = 0;
  auto take = [&](size_t bytes) { char* r = w + o; o = (o + bytes + 255) & ~(size_t)255; return r; };
  P.Wenc  = (u16*)take(4096ull * 1536 * 2);
  P.Wencp = (u16*)take(4096ull * 1536 * 2);
  P.Wdec  = (u16*)take(4096ull * 2048 * 2);
  P.wihP  = (u16*)take(4096ull * 512 * 2);
  P.linT  = (u16*)take(1024ull * 512 * 2);
  P.tpw   = (u16*)take(66ull * 1024 * 2);
  P.bias_e    = (float*)take(4096 * 4);
  P.bias_ep   = (float*)take(4096 * 4);
  P.bias_d    = (float*)take(4096 * 4);
  P.bias_part = (float*)take(32768 * 4);
  P.xf  = (u16*)take(10ull * 256 * 512 * 2);
  P.zf  = (u16*)take(10ull * 256 * 512 * 2);
  P.he  = (u16*)take(11ull * 256 * 1024 * 2);
  P.hp  = (u16*)take(11ull * 256 * 1024 * 2);
  P.hs  = (u16*)take(25ull * 256 * 1024 * 2);
  P.atth = (u16*)take(25ull * 256 * 1024 * 2);
  P.c_pub = (float*)take(2ull * 256 * 1024 * 4);
  P.p1    = (unsigned long long*)take(128ull * 4096 * 8);
  P.flag1 = (unsigned*)take(128 * 64);
  P.bar   = (unsigned*)take(16 * 64);
  P.out = (float*)d_out;

  if (o > ws_size) return;  // workspace too small: fail cleanly, no corruption

  hipFuncSetAttribute((const void*)model_kernel,
                      hipFuncAttributeMaxDynamicSharedMemorySize, SMEM_BYTES);

  void* args[] = { &P };
  hipLaunchCooperativeKernel((const void*)model_kernel, dim3(NBLK, 1, 1),
                             dim3(NTHR, 1, 1), args, SMEM_BYTES, stream);
}

// Round 5
// 905.827 us; speedup vs baseline: 1.3842x; 1.3842x over previous
//
#include <hip/hip_runtime.h>
#include <hip/hip_bf16.h>
#include <hip/hip_cooperative_groups.h>

namespace cg = cooperative_groups;

#define DEV __device__ __forceinline__

typedef unsigned short u16;
typedef short bf16x8_t __attribute__((ext_vector_type(8)));
typedef float f32x4_t __attribute__((ext_vector_type(4)));

// Model dims: B=256 H=1024 F=512 P=66 T_IN=10 T_OUT=25, gates 4H=4096
// enc K = F+H = 1536 ; dec split: role0 hd@Wx (K=1024) + role1 atth@whh (K=1024)
constexpr int NBLK = 256;
constexpr int NTHR = 512;
constexpr int NT_ALL = NBLK * NTHR;
constexpr size_t HSTRIDE = 256 * 1024;
constexpr int SMEM_BYTES = 98304;   // dynamic LDS: A 4x8KB @0, B 4x16KB @32K

struct Params {
  const float *x, *z, *resid, *tf_w, *tf_b;
  const float *e_wih, *e_whh, *e_bih, *e_bhh;
  const float *p_wih, *p_whh, *p_bih, *p_bhh;
  const float *d_wih, *d_whh, *d_bih, *d_bhh;
  const float *lin_w, *lin_b, *tp_w, *tp_b;
  u16 *Wenc, *Wencp, *Wdec, *wihP, *linT, *tpw;
  float *bias_e, *bias_ep, *bias_d, *bias_part;
  u16 *xf, *zf;
  u16 *he, *hp;            // 11 step-buffers each
  u16 *hs;                 // 25 decoder h buffers
  u16 *atth;               // 25 step-buffers
  float *c_pub;            // 2 ping-pong f32 [256][1024]
  unsigned long long *px;  // 2 x 128 tiles x 4096 u64, COALESCED [i*512+tid]
  unsigned *flag1;         // 128 flags (lane*32+jj), 64B stride
  unsigned *bar;           // ctr[i*16]: 0..7 full, 8..15 enc groups, 16..23 lanes
  float *out;
};

DEV float b2f(u16 v) { unsigned u = ((unsigned)v) << 16; float f; __builtin_memcpy(&f, &u, 4); return f; }
DEV u16 f2b(float f) {
  unsigned u; __builtin_memcpy(&u, &f, 4);
  unsigned r = u + 0x7fffu + ((u >> 16) & 1u);   // RNE
  return (u16)(r >> 16);
}
DEV unsigned pk2(float a, float b) { return (unsigned)f2b(a) | ((unsigned)f2b(b) << 16); }
DEV uint4 cvt8(const float* s) {
  float4 a = *(const float4*)s;
  float4 b = *(const float4*)(s + 4);
  uint4 r;
  r.x = pk2(a.x, a.y); r.y = pk2(a.z, a.w);
  r.z = pk2(b.x, b.y); r.w = pk2(b.z, b.w);
  return r;
}
DEV float sigm(float x) { return 1.0f / (1.0f + __expf(-x)); }
DEV f32x4_t fzero4() { f32x4_t v = {0.f, 0.f, 0.f, 0.f}; return v; }

DEV void gll16(const void* g, void* l) {
  __builtin_amdgcn_global_load_lds(
      (const __attribute__((address_space(1))) void*)g,
      (__attribute__((address_space(3))) void*)l, 16, 0, 0);
}

template <typename T> DEV void st_wt(T* p, T v) {
  __hip_atomic_store(p, v, __ATOMIC_RELAXED, __HIP_MEMORY_SCOPE_AGENT);
}
template <typename T> DEV T ld_byp(const T* p) {
  return __hip_atomic_load(p, __ATOMIC_RELAXED, __HIP_MEMORY_SCOPE_AGENT);
}

// ---- fence-free barriers: monotonic counters, no cache flush ----
DEV void fullbar(unsigned* ctrs, int myidx, unsigned tgt, int tid) {
  asm volatile("s_waitcnt vmcnt(0)" ::: "memory");
  __syncthreads();
  if (tid == 0) atomicAdd(&ctrs[myidx * 16], 1u);
  if (tid < 8) { while (ld_byp(&ctrs[tid * 16]) < tgt) __builtin_amdgcn_s_sleep(2); }
  __syncthreads();
}
DEV void gbar(unsigned* ctrs, int cbase, int myidx, unsigned tgt, int tid) {
  asm volatile("s_waitcnt vmcnt(0)" ::: "memory");
  __syncthreads();
  if (tid == 0) atomicAdd(&ctrs[(cbase + myidx) * 16], 1u);
  if (tid < 4) { while (ld_byp(&ctrs[(cbase + tid) * 16]) < tgt) __builtin_amdgcn_s_sleep(2); }
  __syncthreads();
}
DEV void lanebar(unsigned* ctrs, int cbase, unsigned tgt, int j, int tid) {
  asm volatile("s_waitcnt vmcnt(0)" ::: "memory");
  __syncthreads();
  if (tid == 0) atomicAdd(&ctrs[(cbase + (j & 1)) * 16], 1u);
  if (tid < 2) { while (ld_byp(&ctrs[(cbase + tid) * 16]) < tgt) __builtin_amdgcn_s_sleep(2); }
  __syncthreads();
}

// ------------- 64m x 128n tile bf16 GEMM, 8 waves of 32x32 ----------------
// LDS: lA = sm[0..32K) 4 slots x 8KB; lB = sm[32K..96K) 4 slots x 16KB.
// slot(ks) = (ks+2)&3  (prestage of ks=0,1 lands in PHYSICAL slots 2,3 which
// sit above 64K and are never aliased by attention/epilogue overlays < 49K).
// Source-side XOR swizzle (16B unit ^= row&7) + same XOR on ds_read_b128.
// PM: 0 = stage A+B slots 0,1 at entry; 1 = caller prestaged A+B slots 0,1;
//     2 = caller prestaged B slots 0,1 (drained); A staged at entry.
template <int PM>
DEV void gemm64(const u16* __restrict__ xa, int ldx, int xcols,
                const u16* __restrict__ ha, int ldh,
                const u16* __restrict__ wsrc, int ldw, int K,
                int m0, int n0, int tid, char* sm, f32x4_t acc[4]) {
  char* lA = sm;
  char* lB = sm + 32768;
  const int NK = K >> 6;
  const int row = tid >> 3;
  const int usw = ((tid & 7) ^ (row & 7)) * 8;
  const int wv = tid >> 6;
  char* laD = lA + (wv << 10);
  char* lbD = lB + (wv << 10);
  const u16* aX = xa + (size_t)(m0 + row) * ldx + usw;
  const u16* aH = ha + (size_t)(m0 + row) * ldh + usw - xcols;
  const u16* bW0 = wsrc + (size_t)(n0 + row) * ldw + usw;
  const u16* bW1 = bW0 + (size_t)64 * ldw;

  auto sA = [&](int ks) {
    const int k0 = ks << 6;
    const u16* g = (k0 < xcols) ? (aX + k0) : (aH + k0);
    gll16(g, laD + (((ks + 2) & 3) << 13));
  };
  auto sB = [&](int ks) {
    const int k0 = ks << 6;
    const int so = ((ks + 2) & 3) << 14;
    gll16(bW0 + k0, lbD + so);
    gll16(bW1 + k0, lbD + so + 8192);
  };

  const int l = tid & 63, l15 = l & 15, lhi = l >> 4;
  const int wr = wv >> 2, wc = wv & 3;   // 2m x 4n wave grid, 32x32 wave tile
  const int rA0 = wr * 32 + l15, rA1 = rA0 + 16;
  const int nB0 = wc * 32 + l15, nB1 = nB0 + 16;
  const int a00 = rA0 * 128 + ((lhi ^ (rA0 & 7)) << 4);
  const int a01 = rA0 * 128 + (((lhi + 4) ^ (rA0 & 7)) << 4);
  const int a10 = rA1 * 128 + ((lhi ^ (rA1 & 7)) << 4);
  const int a11 = rA1 * 128 + (((lhi + 4) ^ (rA1 & 7)) << 4);
  const int b00 = nB0 * 128 + ((lhi ^ (nB0 & 7)) << 4);
  const int b01 = nB0 * 128 + (((lhi + 4) ^ (nB0 & 7)) << 4);
  const int b10 = nB1 * 128 + ((lhi ^ (nB1 & 7)) << 4);
  const int b11 = nB1 * 128 + (((lhi + 4) ^ (nB1 & 7)) << 4);

  if (PM == 0) { sA(0); sB(0); sA(1); sB(1); }
  if (PM == 2) { sA(0); sA(1); }

#pragma unroll 1
  for (int ks = 0; ks < NK; ++ks) {
    if (ks + 2 < NK) { sA(ks + 2); sB(ks + 2); }
    if (PM == 2 && ks == 0)  asm volatile("s_waitcnt vmcnt(4)" ::: "memory");
    else if (ks + 2 < NK)    asm volatile("s_waitcnt vmcnt(6)" ::: "memory");
    else if (ks + 2 == NK)   asm volatile("s_waitcnt vmcnt(3)" ::: "memory");
    else                     asm volatile("s_waitcnt vmcnt(0)" ::: "memory");
    __builtin_amdgcn_s_barrier();
    const char* A  = lA + (((ks + 2) & 3) << 13);
    const char* Bq = lB + (((ks + 2) & 3) << 14);
#pragma unroll
    for (int kh = 0; kh < 2; ++kh) {
      bf16x8_t va0 = *(const bf16x8_t*)(A + (kh ? a01 : a00));
      bf16x8_t va1 = *(const bf16x8_t*)(A + (kh ? a11 : a10));
      bf16x8_t vb0 = *(const bf16x8_t*)(Bq + (kh ? b01 : b00));
      bf16x8_t vb1 = *(const bf16x8_t*)(Bq + (kh ? b11 : b10));
      acc[0] = __builtin_amdgcn_mfma_f32_16x16x32_bf16(va0, vb0, acc[0], 0, 0, 0);
      acc[1] = __builtin_amdgcn_mfma_f32_16x16x32_bf16(va0, vb1, acc[1], 0, 0, 0);
      acc[2] = __builtin_amdgcn_mfma_f32_16x16x32_bf16(va1, vb0, acc[2], 0, 0, 0);
      acc[3] = __builtin_amdgcn_mfma_f32_16x16x32_bf16(va1, vb1, acc[3], 0, 0, 0);
    }
  }
  asm volatile("s_waitcnt lgkmcnt(0)" ::: "memory");
  __builtin_amdgcn_s_barrier();
}

// Prestage helpers (must match gemm64's addressing/slot mapping exactly)
DEV void preA(const u16* src, int lds_, int m0, int tid, char* sm, int ks) {
  const int row = tid >> 3, usw = ((tid & 7) ^ (row & 7)) * 8, wv = tid >> 6;
  gll16(src + (size_t)(m0 + row) * lds_ + (ks << 6) + usw,
        sm + (wv << 10) + (((ks + 2) & 3) << 13));
}
DEV void preB(const u16* w, int ldw, int n0, int tid, char* sm, int ks) {
  const int row = tid >> 3, usw = ((tid & 7) ^ (row & 7)) * 8, wv = tid >> 6;
  char* d = sm + 32768 + (wv << 10) + (((ks + 2) & 3) << 14);
  gll16(w + (size_t)(n0 + row) * ldw + (ks << 6) + usw, d);
  gll16(w + (size_t)(n0 + 64 + row) * ldw + (ks << 6) + usw, d + 8192);
}

// ----------------- LSTM pointwise epilogue, c in registers -----------------
// Overlay [64][128] f32 at sm[0..32K) (aliases A slots; B phys slots 2,3 safe).
DEV void lstm_ep(const f32x4_t acc[4], int tid, char* sm,
                 const float* __restrict__ bias, float cc[4],
                 const float* __restrict__ cinit,
                 u16* __restrict__ hw, float* __restrict__ cpub,
                 int m0, int n0) {
  float* gl = (float*)sm;
  const int l = tid & 63, l15 = l & 15, lhi = l >> 4;
  const int wv = tid >> 6, wr = wv >> 2, wc = wv & 3;
#pragma unroll
  for (int mf = 0; mf < 2; ++mf)
#pragma unroll
    for (int nf = 0; nf < 2; ++nf)
#pragma unroll
      for (int qq = 0; qq < 4; ++qq)
        gl[(wr * 32 + mf * 16 + lhi * 4 + qq) * 128 + wc * 32 + nf * 16 + l15] =
            acc[mf * 2 + nf][qq];
  __syncthreads();
#pragma unroll
  for (int it = 0; it < 4; ++it) {
    int idx = it * 512 + tid;            // 2048 items: 64 rows x 32 j
    int r = idx >> 5, jj = idx & 31;
    f32x4_t g4 = *(const f32x4_t*)(gl + r * 128 + jj * 4);
    f32x4_t b4 = *(const f32x4_t*)(bias + n0 + jj * 4);
    float ig = sigm(g4[0] + b4[0]);
    float fg = sigm(g4[1] + b4[1]);
    float g_ = tanhf(g4[2] + b4[2]);
    float og = sigm(g4[3] + b4[3]);
    size_t off = (size_t)(m0 + r) * 1024 + (n0 >> 2) + jj;
    float cold = cinit ? ld_byp(cinit + off) : cc[it];
    float cn = fg * cold + ig * g_;
    cc[it] = cn;
    float hn = og * tanhf(cn);
    st_wt(&hw[off], f2b(hn));
    if (cpub) st_wt(&cpub[off], cn);
  }
  __syncthreads();
}

DEV void wx_store(const f32x4_t acc[4], int tid, u16* __restrict__ Wdec,
                  int m0, int n0) {
  const int l = tid & 63, l15 = l & 15, lhi = l >> 4;
  const int wv = tid >> 6, wr = wv >> 2, wc = wv & 3;
#pragma unroll
  for (int mf = 0; mf < 2; ++mf)
#pragma unroll
    for (int nf = 0; nf < 2; ++nf)
#pragma unroll
      for (int qq = 0; qq < 4; ++qq) {
        int r = m0 + wr * 32 + mf * 16 + lhi * 4 + qq;
        int c = n0 + wc * 32 + nf * 16 + l15;
        st_wt(&Wdec[(size_t)r * 2048 + c], f2b(acc[mf * 2 + nf][qq]));
      }
}

// partial exchange — COALESCED: instruction i writes 512 contiguous u64
DEV void px_store(const f32x4_t acc[4], int tid, unsigned long long* base) {
#pragma unroll
  for (int i = 0; i < 8; ++i) {
    float lo = acc[i >> 1][(i & 1) * 2 + 0];
    float hi = acc[i >> 1][(i & 1) * 2 + 1];
    unsigned a_, b_; __builtin_memcpy(&a_, &lo, 4); __builtin_memcpy(&b_, &hi, 4);
    st_wt(base + (size_t)i * 512 + tid,
          (unsigned long long)a_ | ((unsigned long long)b_ << 32));
  }
}
DEV void px_merge(f32x4_t acc[4], int tid, const unsigned long long* base) {
#pragma unroll
  for (int i = 0; i < 8; ++i) {
    unsigned long long u = ld_byp(base + (size_t)i * 512 + tid);
    unsigned a_ = (unsigned)u, b_ = (unsigned)(u >> 32);
    float lo, hi; __builtin_memcpy(&lo, &a_, 4); __builtin_memcpy(&hi, &b_, 4);
    acc[i >> 1][(i & 1) * 2 + 0] += lo;
    acc[i >> 1][(i & 1) * 2 + 1] += hi;
  }
}

// ------------------- phase 0: ToFeature (block-cooperative) ----------------
DEV void phase0_tf(const Params& p, int bid, int tid, char* sm) {
  float* xs = (float*)sm;            // [10][66]
  float* zs = (float*)(sm + 2688);
  for (int g = tid; g < 660; g += NTHR) {
    int t = g / 66, qd = g - t * 66;
    xs[g] = p.x[((size_t)bid * 10 + t) * 66 + qd];
    zs[g] = p.z[((size_t)bid * 10 + t) * 66 + qd];
  }
  __syncthreads();
  const int n = tid;
  float accx[10], accz[10];
  float bn = p.tf_b[n];
#pragma unroll
  for (int t = 0; t < 10; ++t) { accx[t] = bn; accz[t] = bn; }
  const float* wrow = p.tf_w + (size_t)n * 66;
  for (int k = 0; k < 66; ++k) {
    float wk = wrow[k];
#pragma unroll
    for (int t = 0; t < 10; ++t) {
      accx[t] = fmaf(wk, xs[t * 66 + k], accx[t]);
      accz[t] = fmaf(wk, zs[t * 66 + k], accz[t]);
    }
  }
#pragma unroll
  for (int t = 0; t < 10; ++t) {
    p.xf[(size_t)t * 131072 + (size_t)bid * 512 + n] = f2b(accx[t]);
    p.zf[(size_t)t * 131072 + (size_t)bid * 512 + n] = f2b(accz[t]);
  }
  __syncthreads();
}

// --------------------------- phase 0a: conversions -------------------------
DEV void phase0a(const Params& p, int gtid) {
  for (int g = gtid; g < 786432; g += NT_ALL) {     // enc/encp 4096 x 192 units
    int row = g / 192;
    int u = g - row * 192;
    int k = u * 8;
    int nsrc = (row & 3) * 1024 + (row >> 2);       // gate-interleaved rows
    const float* s1 = (k < 512) ? (p.e_wih + (size_t)nsrc * 512 + k)
                                : (p.e_whh + (size_t)nsrc * 1024 + (k - 512));
    ((uint4*)p.Wenc)[g] = cvt8(s1);
    const float* s2 = (k < 512) ? (p.p_wih + (size_t)nsrc * 512 + k)
                                : (p.p_whh + (size_t)nsrc * 1024 + (k - 512));
    ((uint4*)p.Wencp)[g] = cvt8(s2);
  }
  for (int g = gtid; g < 524288; g += NT_ALL) {     // dec whh -> Wdec[:,1024:]
    int row = g >> 7, u = g & 127;
    int nsrc = (row & 3) * 1024 + (row >> 2);
    ((uint4*)p.Wdec)[row * 256 + 128 + u] = cvt8(p.d_whh + (size_t)nsrc * 1024 + u * 8);
  }
  for (int g = gtid; g < 262144; g += NT_ALL) {     // dec wih (gate-permuted)
    int row = g >> 6, u = g & 63;
    int nsrc = (row & 3) * 1024 + (row >> 2);
    ((uint4*)p.wihP)[g] = cvt8(p.d_wih + (size_t)nsrc * 512 + u * 8);
  }
  for (int g = gtid; g < 524288; g += NT_ALL) {     // lin_w transpose
    int f = g >> 10, h = g & 1023;
    p.linT[(size_t)h * 512 + f] = f2b(p.lin_w[g]);
  }
  for (int g = gtid; g < 8448; g += NT_ALL)
    ((uint4*)p.tpw)[g] = cvt8(p.tp_w + g * 8);
  for (int g = gtid; g < 4096; g += NT_ALL) {       // enc biases
    int nsrc = (g & 3) * 1024 + (g >> 2);
    p.bias_e[g]  = p.e_bih[nsrc] + p.e_bhh[nsrc];
    p.bias_ep[g] = p.p_bih[nsrc] + p.p_bhh[nsrc];
  }
  for (int g = gtid; g < 32768; g += NT_ALL) {      // bias_d partials (wih@lin_b)
    int cell = g >> 3, sub = g & 7;
    int nsrc = (cell & 3) * 1024 + (cell >> 2);
    const float* wr_ = p.d_wih + (size_t)nsrc * 512 + sub * 64;
    const float* lb = p.lin_b + sub * 64;
    float s = 0.f;
    for (int f = 0; f < 64; ++f) s += wr_[f] * lb[f];
    p.bias_part[g] = s;
  }
  uint4 zz; zz.x = zz.y = zz.z = zz.w = 0u;         // zero h0 for both encoders
  for (int g = gtid; g < 32768; g += NT_ALL) { ((uint4*)p.he)[g] = zz; ((uint4*)p.hp)[g] = zz; }
}

// --------------------------- attention (1 row / block) ---------------------
// LDS: catl at sm[0..43008), cl at +43008, sc at +47104 (< 49152; B phys
// slots 2,3 at sm[64K..96K) survive).
DEV void attention(const Params& p, const u16* hd_prev, const float* cpub,
                   u16* atth_s, int b, int tid, char* sm) {
  u16*   catl = (u16*)sm;
  float* cl   = (float*)(sm + 43008);
  float* sc   = (float*)(sm + 47104);
  for (int g = tid; g < 2688; g += NTHR) {
    int t = g >> 7, hu = g & 127;
    const u16* src;
    if (t < 10)       src = p.he + (size_t)(t + 1) * HSTRIDE;
    else if (t == 10) src = hd_prev;
    else              src = p.hp + (size_t)(t - 10) * HSTRIDE;
    ((uint4*)catl)[g] = *(const uint4*)(src + (size_t)b * 1024 + hu * 8);
  }
  for (int g = tid; g < 512; g += NTHR) {
    unsigned long long v = ld_byp(((const unsigned long long*)(cpub + (size_t)b * 1024)) + g);
    ((unsigned long long*)cl)[g] = v;
  }
  __syncthreads();
  const int wv = tid >> 6, l = tid & 63;
  for (int t = wv; t < 21; t += 8) {
    float s = 0.f;
    const u16* cr = catl + t * 1024;
    for (int hh = l; hh < 1024; hh += 64) s += cl[hh] * b2f(cr[hh]);
#pragma unroll
    for (int o = 32; o; o >>= 1) s += __shfl_down(s, o);
    if (l == 0) sc[t] = s;
  }
  __syncthreads();
  float m = -1e30f;
#pragma unroll
  for (int t = 0; t < 21; ++t) m = fmaxf(m, sc[t]);
  float e[21]; float den = 0.f;
#pragma unroll
  for (int t = 0; t < 21; ++t) { e[t] = __expf(sc[t] - m); den += e[t]; }
  float inv = 1.0f / den;
  const int h0 = tid * 2;
  float a0 = 0.f, a1 = 0.f;
#pragma unroll
  for (int t = 0; t < 21; ++t) {
    float w_ = e[t] * inv;
    unsigned v = *(const unsigned*)(catl + t * 1024 + h0);
    a0 += w_ * b2f((u16)(v & 0xffff));
    a1 += w_ * b2f((u16)(v >> 16));
  }
  st_wt(((unsigned*)(atth_s + (size_t)b * 1024)) + tid, pk2(a0, a1));
  __syncthreads();   // catl reads done before gemm stages reuse this region
}

// ------------------------- final projection (1 b / block) ------------------
DEV void finalproj(const Params& p, int b, int tid, char* sm) {
  u16* hl = (u16*)sm;                     // [25][1024] bf16 = 51200 B
  for (int g = tid; g < 3200; g += NTHR) {
    int t = g >> 7, hu = g & 127;
    ((uint4*)hl)[g] = *(const uint4*)(p.hs + ((size_t)(t * 256 + b)) * 1024 + hu * 8);
  }
  __syncthreads();
  if (tid < 330) {
    int pcol = tid % 66, tg = tid / 66;
    float acc[5] = {0.f, 0.f, 0.f, 0.f, 0.f};
    const u16* wrow = p.tpw + (size_t)pcol * 1024;
    for (int hc = 0; hc < 128; ++hc) {
      uint4 wv4 = ((const uint4*)wrow)[hc];
      float wf[8];
      wf[0] = b2f(wv4.x & 0xffff); wf[1] = b2f(wv4.x >> 16);
      wf[2] = b2f(wv4.y & 0xffff); wf[3] = b2f(wv4.y >> 16);
      wf[4] = b2f(wv4.z & 0xffff); wf[5] = b2f(wv4.z >> 16);
      wf[6] = b2f(wv4.w & 0xffff); wf[7] = b2f(wv4.w >> 16);
#pragma unroll
      for (int r = 0; r < 5; ++r) {
        int t = tg * 5 + r;
        uint4 hv = ((const uint4*)(hl + t * 1024))[hc];
        float s;
        s  = wf[0] * b2f(hv.x & 0xffff) + wf[1] * b2f(hv.x >> 16);
        s += wf[2] * b2f(hv.y & 0xffff) + wf[3] * b2f(hv.y >> 16);
        s += wf[4] * b2f(hv.z & 0xffff) + wf[5] * b2f(hv.z >> 16);
        s += wf[6] * b2f(hv.w & 0xffff) + wf[7] * b2f(hv.w >> 16);
        acc[r] += s;
      }
    }
    float bb = p.tp_b[pcol];
#pragma unroll
    for (int r = 0; r < 5; ++r) {
      int t = tg * 5 + r;
      size_t o = (size_t)b * 1650 + (size_t)t * 66 + pcol;
      p.out[o] = acc[r] + bb + p.resid[o];
    }
  }
}

// ------------------------------- main kernel -------------------------------
__global__ __launch_bounds__(NTHR) void model_kernel(Params p) {
  cg::grid_group gg = cg::this_grid();
  extern __shared__ __align__(16) char sm[];
  const int tid = threadIdx.x;
  const int bid = blockIdx.x;
  const int gtid = bid * NTHR + tid;

  phase0_tf(p, bid, tid, sm);
  phase0a(p, gtid);
  if (bid == 0) {
    if (tid < 24)  st_wt(&p.bar[tid * 16], 0u);
    if (tid < 128) st_wt(&p.flag1[tid * 16], 0u);
  }
  gg.sync();                      // ONLY full-fence sync (flushes + L2-inv)

  // finalize bias_d
  for (int g = gtid; g < 4096; g += NT_ALL) {
    int nsrc = (g & 3) * 1024 + (g >> 2);
    float s = p.d_bih[nsrc] + p.d_bhh[nsrc];
#pragma unroll
    for (int k8 = 0; k8 < 8; ++k8) s += p.bias_part[g * 8 + k8];
    st_wt(&p.bias_d[g], s);
  }
  // P0b: Wdec[:,0:1024] = (gate-permuted dec_wih) @ lin_w  (lin fused)
#pragma unroll 1
  for (int i = 0; i < 2; ++i) {
    int tt = bid * 2 + i;
    int m0w = (tt & 63) << 6;
    int n0w = (tt >> 6) << 7;
    f32x4_t acc[4] = {fzero4(), fzero4(), fzero4(), fzero4()};
    gemm64<0>(p.wihP, 512, 512, p.wihP, 512, p.linT, 512, 512, m0w, n0w, tid, sm, acc);
    wx_store(acc, tid, p.Wdec, m0w, n0w);
  }

  // Encoder geometry (grid halves): grp0 = enc, grp1 = encp
  const int grp = bid >> 7;
  const int q = bid & 127;
  const int m0 = (q >> 5) << 6;
  const int n0 = (q & 31) << 7;
  const int cb = grp ? 12 : 8;
  const int cidx = q >> 5;

  // Decoder geometry (lane-local role split)
  const int lane = bid >> 6, j = bid & 63;
  const int m0d = lane << 6;
  const int role = j >> 5, jj = j & 31;
  const int n0d = jj << 7;
  const int tixd = lane * 32 + jj;

  const u16* xsrc = grp ? p.zf : p.xf;
  const u16* Wg   = grp ? p.Wencp : p.Wenc;
  u16* hbuf       = grp ? p.hp : p.he;
  const float* bias_g = grp ? p.bias_ep : p.bias_e;

  // prestage encoder t=0, then the post-setup full barrier
  preA(xsrc, 512, m0, tid, sm, 0);
  preB(Wg, 1536, n0, tid, sm, 0);
  preA(xsrc, 512, m0, tid, sm, 1);
  preB(Wg, 1536, n0, tid, sm, 1);
  fullbar(p.bar, bid & 7, 1u * 32, tid);

  float cc[4] = {0.f, 0.f, 0.f, 0.f};

  // P1: encoders, halves fully independent (128-block group barriers)
#pragma unroll 1
  for (int t = 0; t < 10; ++t) {
    f32x4_t acc[4] = {fzero4(), fzero4(), fzero4(), fzero4()};
    gemm64<1>(xsrc + (size_t)t * 131072, 512, 512, hbuf + (size_t)t * HSTRIDE, 1024,
              Wg, 1536, 1536, m0, n0, tid, sm, acc);
    lstm_ep(acc, tid, sm, bias_g, cc, (const float*)0,
            hbuf + (size_t)(t + 1) * HSTRIDE,
            (!grp && t == 9) ? p.c_pub : (float*)0, m0, n0);
    if (t < 9) {
      preA(xsrc + (size_t)(t + 1) * 131072, 512, m0, tid, sm, 0);
      preB(Wg, 1536, n0, tid, sm, 0);
      preA(xsrc + (size_t)(t + 1) * 131072, 512, m0, tid, sm, 1);
      preB(Wg, 1536, n0, tid, sm, 1);
    } else {
      // prestage the DECODE-role B panel (decode geometry, not encoder's)
      const u16* wd = role ? (p.Wdec + 1024) : p.Wdec;
      preB(wd, 2048, n0d, tid, sm, 0);
      preB(wd, 2048, n0d, tid, sm, 1);
    }
    gbar(p.bar, cb, cidx, (unsigned)(t + 1) * 32, tid);
  }
  fullbar(p.bar, bid & 7, 2u * 32, tid);

  // P3: decoder, lane-local role split. role0: hd@Wx -> px; role1: att-gemm,
  // merge partner partials, epilogue. All blocks: attention (1 row each).
  float cd[4] = {0.f, 0.f, 0.f, 0.f};
  unsigned long long* px0 = p.px + (size_t)tixd * 4096;
  unsigned long long* px1 = p.px + (size_t)(128 + tixd) * 4096;
#pragma unroll 1
  for (int s = 0; s < 25; ++s) {
    const u16* hd_prev = (s == 0) ? (p.he + (size_t)10 * HSTRIDE)
                                  : (p.hs + (size_t)(s - 1) * HSTRIDE);
    u16* atth_s = p.atth + (size_t)s * HSTRIDE;
    attention(p, hd_prev, p.c_pub + (size_t)(s & 1) * 262144, atth_s, bid, tid, sm);
    lanebar(p.bar, 16 + lane * 2, (unsigned)(2 * s + 1) * 32, j, tid);
    f32x4_t acc[4] = {fzero4(), fzero4(), fzero4(), fzero4()};
    unsigned long long* pxs = (s & 1) ? px1 : px0;
    if (role == 0) {
      gemm64<2>(hd_prev, 1024, 1024, hd_prev, 1024, p.Wdec, 2048, 1024,
                m0d, n0d, tid, sm, acc);
      px_store(acc, tid, pxs);
      asm volatile("s_waitcnt vmcnt(0)" ::: "memory");
      __syncthreads();
      if (tid == 0) st_wt(&p.flag1[tixd * 16], (unsigned)(s + 1));
      preB(p.Wdec, 2048, n0d, tid, sm, 0);
      preB(p.Wdec, 2048, n0d, tid, sm, 1);
    } else {
      gemm64<2>(atth_s, 1024, 1024, atth_s, 1024, p.Wdec + 1024, 2048, 1024,
                m0d, n0d, tid, sm, acc);
      if (tid == 0) {
        while (ld_byp(&p.flag1[tixd * 16]) < (unsigned)(s + 1)) __builtin_amdgcn_s_sleep(2);
      }
      __syncthreads();
      px_merge(acc, tid, pxs);
      lstm_ep(acc, tid, sm, p.bias_d, cd,
              (s == 0) ? p.c_pub : (const float*)0,
              p.hs + (size_t)s * HSTRIDE,
              p.c_pub + (size_t)((s + 1) & 1) * 262144, m0d, n0d);
      preB(p.Wdec + 1024, 2048, n0d, tid, sm, 0);
      preB(p.Wdec + 1024, 2048, n0d, tid, sm, 1);
    }
    lanebar(p.bar, 16 + lane * 2, (unsigned)(2 * s + 2) * 32, j, tid);
  }

  // P4: out = dec_h @ tp_w.T + tp_b + for_resid
  finalproj(p, bid, tid, sm);
}

// ------------------------------- host launch -------------------------------
extern "C" void kernel_launch(void* const* d_in, const int* in_sizes, int n_in,
                              void* d_out, int out_size, void* d_ws, size_t ws_size,
                              hipStream_t stream) {
  (void)in_sizes; (void)n_in; (void)out_size;
  Params P;
  P.x     = (const float*)d_in[0];
  P.z     = (const float*)d_in[1];
  P.resid = (const float*)d_in[2];
  P.tf_w  = (const float*)d_in[3];
  P.tf_b  = (const float*)d_in[4];
  P.e_wih = (const float*)d_in[5];
  P.e_whh = (const float*)d_in[6];
  P.e_bih = (const float*)d_in[7];
  P.e_bhh = (const float*)d_in[8];
  P.p_wih = (const float*)d_in[9];
  P.p_whh = (const float*)d_in[10];
  P.p_bih = (const float*)d_in[11];
  P.p_bhh = (const float*)d_in[12];
  P.d_wih = (const float*)d_in[13];
  P.d_whh = (const float*)d_in[14];
  P.d_bih = (const float*)d_in[15];
  P.d_bhh = (const float*)d_in[16];
  P.lin_w = (const float*)d_in[17];
  P.lin_b = (const float*)d_in[18];
  P.tp_w  = (const float*)d_in[19];
  P.tp_b  = (const float*)d_in[20];

  char* w = (char*)d_ws;
  size_t o = 0;
  auto take = [&](size_t bytes) { char* r = w + o; o = (o + bytes + 255) & ~(size_t)255; return r; };
  P.Wenc  = (u16*)take(4096ull * 1536 * 2);
  P.Wencp = (u16*)take(4096ull * 1536 * 2);
  P.Wdec  = (u16*)take(4096ull * 2048 * 2);
  P.wihP  = (u16*)take(4096ull * 512 * 2);
  P.linT  = (u16*)take(1024ull * 512 * 2);
  P.tpw   = (u16*)take(66ull * 1024 * 2);
  P.bias_e    = (float*)take(4096 * 4);
  P.bias_ep   = (float*)take(4096 * 4);
  P.bias_d    = (float*)take(4096 * 4);
  P.bias_part = (float*)take(32768 * 4);
  P.xf  = (u16*)take(10ull * 256 * 512 * 2);
  P.zf  = (u16*)take(10ull * 256 * 512 * 2);
  P.he  = (u16*)take(11ull * 256 * 1024 * 2);
  P.hp  = (u16*)take(11ull * 256 * 1024 * 2);
  P.hs  = (u16*)take(25ull * 256 * 1024 * 2);
  P.atth = (u16*)take(25ull * 256 * 1024 * 2);
  P.c_pub = (float*)take(2ull * 256 * 1024 * 4);
  P.px    = (unsigned long long*)take(2ull * 128 * 4096 * 8);
  P.flag1 = (unsigned*)take(128 * 64);
  P.bar   = (unsigned*)take(24 * 64);
  P.out = (float*)d_out;

  if (o > ws_size) return;  // workspace too small: fail cleanly, no corruption

  hipFuncSetAttribute((const void*)model_kernel,
                      hipFuncAttributeMaxDynamicSharedMemorySize, SMEM_BYTES);

  void* args[] = { &P };
  hipLaunchCooperativeKernel((const void*)model_kernel, dim3(NBLK, 1, 1),
                             dim3(NTHR, 1, 1), args, SMEM_BYTES, stream);
}